// Round 5
// baseline (432.596 us; speedup 1.0000x reference)
//
#include <hip/hip_runtime.h>
#include <math.h>

constexpr int NB = 32;     // batch
constexpr int NL = 512;    // seq len
constexpr int NH = 1024;   // hidden
constexpr int NT = 67;     // tags

// ---------------- shfl helpers ----------------
__device__ __forceinline__ float wave_max_f(float v) {
#pragma unroll
  for (int o = 32; o > 0; o >>= 1) v = fmaxf(v, __shfl_xor(v, o));
  return v;
}
__device__ __forceinline__ float wave_min_f(float v) {
#pragma unroll
  for (int o = 32; o > 0; o >>= 1) v = fminf(v, __shfl_xor(v, o));
  return v;
}
__device__ __forceinline__ float wave_sum_f(float v) {
#pragma unroll
  for (int o = 32; o > 0; o >>= 1) v += __shfl_xor(v, o);
  return v;
}
__device__ __forceinline__ int wave_sum_i(int v) {
#pragma unroll
  for (int o = 32; o > 0; o >>= 1) v += __shfl_xor(v, o);
  return v;
}

// ---------------- DPP wave reductions ----------------
#define DPPF(OLDV, X, CTRL)                                                     \
  __int_as_float(__builtin_amdgcn_update_dpp(__float_as_int(OLDV),              \
                                             __float_as_int(X), (CTRL), 0xf,   \
                                             0xf, false))

__device__ __forceinline__ float wave_max_dpp(float x) {  // exact max, broadcast
  x = fmaxf(x, DPPF(x, x, 0x111));
  x = fmaxf(x, DPPF(x, x, 0x112));
  x = fmaxf(x, DPPF(x, x, 0x114));
  x = fmaxf(x, DPPF(x, x, 0x118));
  x = fmaxf(x, DPPF(x, x, 0x142));
  x = fmaxf(x, DPPF(x, x, 0x143));
  return __int_as_float(__builtin_amdgcn_readlane(__float_as_int(x), 63));
}
__device__ __forceinline__ float wave_sum_dpp(float x) {  // broadcast
  x += DPPF(0.f, x, 0x111);
  x += DPPF(0.f, x, 0x112);
  x += DPPF(0.f, x, 0x114);
  x += DPPF(0.f, x, 0x118);
  x += DPPF(0.f, x, 0x142);
  x += DPPF(0.f, x, 0x143);
  return __int_as_float(__builtin_amdgcn_readlane(__float_as_int(x), 63));
}

#define LGKM_BARRIER() asm volatile("s_waitcnt lgkmcnt(0)" ::: "memory")

__device__ __forceinline__ float rdlane(float v, int l) {
  return __int_as_float(__builtin_amdgcn_readlane(__float_as_int(v), l));
}

// Σ_{i=0}^{66} p_i * ET[i] with p in (PV lanes 0..63, PV2 lanes 0..2).
// readlane->SGPR operand FMAs: no LDS, no lgkm.
#define BCAST_DOT(RES, PV, PV2, ETARR)                                         \
  {                                                                            \
    float _s0 = 0.f, _s1 = 0.f, _s2 = 0.f, _s3 = 0.f;                          \
    _Pragma("unroll") for (int _i = 0; _i < 64; _i += 4) {                     \
      _s0 = fmaf(rdlane(PV, _i + 0), ETARR[_i + 0], _s0);                      \
      _s1 = fmaf(rdlane(PV, _i + 1), ETARR[_i + 1], _s1);                      \
      _s2 = fmaf(rdlane(PV, _i + 2), ETARR[_i + 2], _s2);                      \
      _s3 = fmaf(rdlane(PV, _i + 3), ETARR[_i + 3], _s3);                      \
    }                                                                          \
    _s0 = fmaf(rdlane(PV2, 0), ETARR[64], _s0);                                \
    _s1 = fmaf(rdlane(PV2, 1), ETARR[65], _s1);                                \
    _s2 = fmaf(rdlane(PV2, 2), ETARR[66], _s2);                                \
    RES = (_s0 + _s1) + (_s2 + _s3);                                           \
  }

// ---------------- K1: scores = log_softmax(leaky_relu(hidden) @ W + b) ------
// 256 blocks x 256 threads; 64 rows/block; lane = row; wave = 17-col slice
// (col bases {0,17,34,50}; wave3 overlaps col 50, excluded from its partials).
// W read via UNIFORM loads (scalar path, no DS); A transposed into LDS,
// 128-k chunks, double-buffered, load-early/write-late staging.
// K-accumulation order identical to R4 => bitwise-identical logits.
constexpr int SKC = 128;

__global__ __launch_bounds__(256) void k_scores(const float* __restrict__ hidden,
                                                const float* __restrict__ W,
                                                const float* __restrict__ bias,
                                                float* __restrict__ scores) {
  __shared__ float AT[2][SKC][65];
  __shared__ float Pm[4][64];
  __shared__ float Ps[4][64];

  const int tid = threadIdx.x;
  const int lane = tid & 63;
  const int wv = __builtin_amdgcn_readfirstlane(tid >> 6);  // 0..3
  const size_t r0 = (size_t)blockIdx.x * 64;

  const int cb = (wv == 3) ? 50 : wv * 17;
  const int rstart = (wv == 3) ? 1 : 0;
  const float* __restrict__ Wu = W + cb;  // uniform base

  float acc[17];
#pragma unroll
  for (int i = 0; i < 17; ++i) acc[i] = 0.f;

  float4 st[8];
  // prologue: load + write chunk 0
#pragma unroll
  for (int it = 0; it < 8; ++it) {
    int flat = it * 256 + tid;
    int row = flat >> 5, k4 = flat & 31;
    st[it] = *reinterpret_cast<const float4*>(&hidden[(r0 + row) * NH + k4 * 4]);
  }
#pragma unroll
  for (int it = 0; it < 8; ++it) {
    int flat = it * 256 + tid;
    int row = flat >> 5, k4 = flat & 31;
    float4 v = st[it];
    v.x = fmaxf(v.x, 0.01f * v.x);
    v.y = fmaxf(v.y, 0.01f * v.y);
    v.z = fmaxf(v.z, 0.01f * v.z);
    v.w = fmaxf(v.w, 0.01f * v.w);
    AT[0][k4 * 4 + 0][row] = v.x;
    AT[0][k4 * 4 + 1][row] = v.y;
    AT[0][k4 * 4 + 2][row] = v.z;
    AT[0][k4 * 4 + 3][row] = v.w;
  }
  __syncthreads();

  for (int ch = 0; ch < 8; ++ch) {
    const int buf = ch & 1;
    if (ch < 7) {  // issue next chunk's global loads early
      const int kn = (ch + 1) * SKC;
#pragma unroll
      for (int it = 0; it < 8; ++it) {
        int flat = it * 256 + tid;
        int row = flat >> 5, k4 = flat & 31;
        st[it] = *reinterpret_cast<const float4*>(&hidden[(r0 + row) * NH + kn + k4 * 4]);
      }
    }
    // compute: k ascending (global order preserved)
    const float* wrow = Wu + (size_t)ch * SKC * NT;
#pragma unroll 2
    for (int k = 0; k < SKC; ++k) {
      float a = AT[buf][k][lane];
      const float* wr = wrow + k * NT;  // uniform -> scalar loads
#pragma unroll
      for (int c = 0; c < 17; ++c) acc[c] = fmaf(a, wr[c], acc[c]);
    }
    if (ch < 7) {  // write staged data into the other buffer
#pragma unroll
      for (int it = 0; it < 8; ++it) {
        int flat = it * 256 + tid;
        int row = flat >> 5, k4 = flat & 31;
        float4 v = st[it];
        v.x = fmaxf(v.x, 0.01f * v.x);
        v.y = fmaxf(v.y, 0.01f * v.y);
        v.z = fmaxf(v.z, 0.01f * v.z);
        v.w = fmaxf(v.w, 0.01f * v.w);
        AT[buf ^ 1][k4 * 4 + 0][row] = v.x;
        AT[buf ^ 1][k4 * 4 + 1][row] = v.y;
        AT[buf ^ 1][k4 * 4 + 2][row] = v.z;
        AT[buf ^ 1][k4 * 4 + 3][row] = v.w;
      }
    }
    __syncthreads();
  }

  // epilogue: bias + row log-softmax (cross-wave via Pm/Ps)
#pragma unroll
  for (int c = 0; c < 17; ++c) acc[c] += bias[cb + c];
  float pm = -INFINITY;
#pragma unroll
  for (int c = 0; c < 17; ++c)
    if (c >= rstart) pm = fmaxf(pm, acc[c]);
  Pm[wv][lane] = pm;
  __syncthreads();
  float M = fmaxf(fmaxf(Pm[0][lane], Pm[1][lane]), fmaxf(Pm[2][lane], Pm[3][lane]));
  float ps = 0.f;
#pragma unroll
  for (int c = 0; c < 17; ++c)
    if (c >= rstart) ps += expf(acc[c] - M);
  Ps[wv][lane] = ps;
  __syncthreads();
  float S = ((Ps[0][lane] + Ps[1][lane]) + (Ps[2][lane] + Ps[3][lane]));
  float lse = M + logf(S);
#pragma unroll
  for (int c = 0; c < 17; ++c)
    if (c >= rstart) scores[(r0 + lane) * NT + cb + c] = acc[c] - lse;
}

// ---------------- K2: 64 blocks x 128 threads ------------------------------
// blocks  0..31: CRF  (wave0: fwd t=1..255 linear-domain; wave1: bwd 511..256)
// blocks 32..63: Viterbi (wave0 fwd + wave1 bwd, junction, ckpt backtrace)
constexpr int VOF_TL = 0;        // f32 Tl[68][68]
constexpr int VOF_TT = 18496;    // f32 TlT[68][68] (transposed)
constexpr int VOF_H1 = 36992;    // u8 h1f[256][68]  fwd backptrs t=1..255
constexpr int VOF_GP = 54400;    // u8 gp[256][68]   bwd fwd-ptrs, idx t-256
constexpr int VOF_FJ = 71808;    // f32 fj[68]
constexpr int VOF_BJ = 72080;    // f32 bj[68]
constexpr int VOF_JP = 72352;    // i32 jp[68]
constexpr int VOF_CKF = 72624;   // u8 ckF[4][68]
constexpr int VOF_CKB = 72896;   // u8 ckB[3][68]
constexpr int VOF_JI = 73104;    // i32 ji[4]
constexpr int LDSV = 73120;

__global__ __launch_bounds__(128) void k_scan(const float* __restrict__ scores,
                                              const float* __restrict__ trans,
                                              const float* __restrict__ startv,
                                              const float* __restrict__ endv,
                                              const int* __restrict__ labels,
                                              const int* __restrict__ maskp,
                                              float* __restrict__ wsA,
                                              float* __restrict__ wsB,
                                              float* __restrict__ wsNum,
                                              float* __restrict__ tags_out) {
  extern __shared__ char smem[];
  const int lane = threadIdx.x & 63;
  const int wid = threadIdx.x >> 6;

  if (blockIdx.x < NB) {
    // ===================== CRF (linear domain, readlane broadcast) =========
    const int b = blockIdx.x;
    const float* sc = scores + (size_t)b * NL * NT;
    const int* mk = maskp + b * NL;

    if (wid == 0) {
      // ---- forward t=1..255 (mask-free: lengths >= 256) ----
      const int* lb = labels + b * NL;
      float ET0[NT];
#pragma unroll
      for (int i = 0; i < NT; ++i) ET0[i] = __expf(trans[i * NT + lane]);
      float E3[3], E3b[3];
      const int r2 = (lane < 3) ? (64 + lane) : 66;
#pragma unroll
      for (int k = 0; k < 3; ++k) {
        E3[k] = __expf(trans[lane * NT + 64 + k]);
        E3b[k] = (lane < 3) ? __expf(trans[r2 * NT + 64 + k]) : 0.f;
      }
      float P = __expf(startv[lane] + sc[lane]);
      float P2 = (lane < 3) ? __expf(startv[64 + lane] + sc[64 + lane]) : 0.f;
      float logsc = 0.f;
      float eA0 = sc[NT + lane];
      float eA1 = (lane < 3) ? sc[NT + 64 + lane] : 0.f;
      float eB0 = sc[2 * NT + lane];
      float eB1 = (lane < 3) ? sc[2 * NT + 64 + lane] : 0.f;
      for (int t = 1; t < 256; ++t) {
        float pe = __expf(eA0);
        float pe2 = (lane < 3) ? __expf(eA1) : 0.f;
        eA0 = eB0;
        eA1 = eB1;
        if (t < 254) {
          eB0 = sc[(t + 2) * NT + lane];
          eB1 = (lane < 3) ? sc[(t + 2) * NT + 64 + lane] : 0.f;
        }
        float S;
        BCAST_DOT(S, P, P2, ET0);
        float x0 = wave_sum_dpp(fmaf(P, E3[0], P2 * E3b[0]));
        float x1 = wave_sum_dpp(fmaf(P, E3[1], P2 * E3b[1]));
        float x2 = wave_sum_dpp(fmaf(P, E3[2], P2 * E3b[2]));
        P = pe * S;
        if (lane < 3) P2 = pe2 * ((lane == 0) ? x0 : ((lane == 1) ? x1 : x2));
        if ((t & 7) == 0) {
          float m = wave_max_dpp(fmaxf(P, P2));
          float inv = 1.0f / m;
          P *= inv;
          P2 *= inv;
          logsc += __logf(m);
        }
      }
      wsA[b * 68 + lane] = logsc + __logf(P);
      if (lane < 3) wsA[b * 68 + 64 + lane] = logsc + __logf(P2);

      // numerator (parallel over t)
      float esum = 0.f, trsum = 0.f;
      int lenc = 0;
#pragma unroll
      for (int rr = 0; rr < 8; ++rr) {
        int t = lane + 64 * rr;
        int m = mk[t];
        int lab = lb[t];
        if (m) {
          esum += sc[t * NT + lab];
          lenc += 1;
          if (t > 0) trsum += trans[lb[t - 1] * NT + lab];
        }
      }
      esum = wave_sum_f(esum);
      trsum = wave_sum_f(trsum);
      int len = wave_sum_i(lenc);
      if (lane == 0) wsNum[b] = startv[lb[0]] + esum + trsum + endv[lb[len - 1]];
    } else {
      // ---- backward t=511..256 (masked steps = identity) ----
      float ER[NT];
#pragma unroll
      for (int j = 0; j < NT; ++j) ER[j] = __expf(trans[lane * NT + j]);
      float EC3[3], EC3b[3];
#pragma unroll
      for (int k = 0; k < 3; ++k) {
        EC3[k] = __expf(trans[(64 + k) * NT + lane]);
        EC3b[k] = (lane < 3) ? __expf(trans[(64 + k) * NT + 64 + lane]) : 0.f;
      }
      float Q = __expf(endv[lane]);
      float Q2 = (lane < 3) ? __expf(endv[64 + lane]) : 0.f;
      float logsc = 0.f;
      float eA0 = sc[511 * NT + lane];
      float eA1 = (lane < 3) ? sc[511 * NT + 64 + lane] : 0.f;
      int mA = mk[511];
      float eB0 = sc[510 * NT + lane];
      float eB1 = (lane < 3) ? sc[510 * NT + 64 + lane] : 0.f;
      int mB = mk[510];
      for (int t = 511; t >= 256; --t) {
        float ue0 = __expf(eA0);
        float ue1 = (lane < 3) ? __expf(eA1) : 0.f;
        int mt = mA;
        eA0 = eB0;
        eA1 = eB1;
        mA = mB;
        if (t > 257) {
          eB0 = sc[(t - 2) * NT + lane];
          eB1 = (lane < 3) ? sc[(t - 2) * NT + 64 + lane] : 0.f;
          mB = mk[t - 2];
        }
        float u = ue0 * Q;
        float u2 = ue1 * Q2;
        float S;
        BCAST_DOT(S, u, u2, ER);
        float x0 = wave_sum_dpp(fmaf(u, EC3[0], u2 * EC3b[0]));
        float x1 = wave_sum_dpp(fmaf(u, EC3[1], u2 * EC3b[1]));
        float x2 = wave_sum_dpp(fmaf(u, EC3[2], u2 * EC3b[2]));
        if (mt) {
          Q = S;
          if (lane < 3) Q2 = (lane == 0) ? x0 : ((lane == 1) ? x1 : x2);
        }
        if ((t & 7) == 0) {
          float m = wave_max_dpp(fmaxf(Q, Q2));
          float inv = 1.0f / m;
          Q *= inv;
          Q2 *= inv;
          logsc += __logf(m);
        }
      }
      wsB[b * 68 + lane] = logsc + __logf(Q);
      if (lane < 3) wsB[b * 68 + 64 + lane] = logsc + __logf(Q2);
    }
  } else {
    // ===================== Viterbi (bidirectional + checkpoints) ===========
    const int b = blockIdx.x - NB;
    const float* sc = scores + (size_t)b * NL * NT;
    const int* mk = maskp + b * NL;
    float* out = tags_out + (size_t)b * NL;
    float* Tl = (float*)(smem + VOF_TL);
    float* TlT = (float*)(smem + VOF_TT);
    unsigned char* h1f = (unsigned char*)(smem + VOF_H1);
    unsigned char* gp = (unsigned char*)(smem + VOF_GP);
    float* fj = (float*)(smem + VOF_FJ);
    float* bj = (float*)(smem + VOF_BJ);
    int* jp = (int*)(smem + VOF_JP);
    unsigned char* ckF = (unsigned char*)(smem + VOF_CKF);
    unsigned char* ckB = (unsigned char*)(smem + VOF_CKB);
    int* ji = (int*)(smem + VOF_JI);

    for (int idx = threadIdx.x; idx < NT * NT; idx += 128) {
      int i = idx / NT, j = idx - i * NT;
      float v = trans[idx];
      Tl[i * 68 + j] = v;
      TlT[j * 68 + i] = v;
    }
    for (int idx = threadIdx.x; idx < 68; idx += 128) {
      Tl[idx * 68 + 67] = 0.f;
      Tl[67 * 68 + idx] = 0.f;
      TlT[idx * 68 + 67] = 0.f;
      TlT[67 * 68 + idx] = 0.f;
    }
    __syncthreads();

    float lmin = 1e30f, lmax = -1e30f;
    for (int idx = lane; idx < NT * NT; idx += 64) {
      int i = idx / NT, j = idx - i * NT;
      float v = Tl[i * 68 + j];
      lmin = fminf(lmin, v);
      lmax = fmaxf(lmax, v);
    }
    const float trspan = wave_min_f(lmin) - wave_max_f(lmax) - 1e-5f;
    int lenc = 0;
#pragma unroll
    for (int rr = 0; rr < 8; ++rr) lenc += (mk[lane + 64 * rr] ? 1 : 0);
    const int len = wave_sum_i(lenc);

    if (wid == 0) {
      // ---- forward half t=1..255 ----
      const int j2col = 64 + (lane & 3);
      float s0 = startv[lane] + sc[lane];
      float s1 = (lane < 3) ? (startv[64 + lane] + sc[64 + lane]) : -INFINITY;
      int cmp = lane, cmp2 = 64 + lane;
      float eA0 = sc[NT + lane];
      float eA1 = (lane < 3) ? sc[NT + 64 + lane] : 0.f;
      float eB0 = sc[2 * NT + lane];
      float eB1 = (lane < 3) ? sc[2 * NT + 64 + lane] : 0.f;
      for (int t = 1; t < 256; ++t) {
        float e0 = eA0, e1 = eA1;
        eA0 = eB0;
        eA1 = eB1;
        if (t < 254) {
          eB0 = sc[(t + 2) * NT + lane];
          eB1 = (lane < 3) ? sc[(t + 2) * NT + 64 + lane] : 0.f;
        }
        float Smax = wave_max_dpp(fmaxf(s0, s1));
        float thr = Smax + trspan;
        unsigned long long cm = __ballot(s0 >= thr);
        unsigned em = (unsigned)__ballot((lane < 3) && (s1 >= thr)) & 7u;
        float m0 = -INFINITY, m1 = -INFINITY;
        int a0i = 0, a1i = 0;
        while (cm) {
          int c0 = (int)__builtin_ctzll(cm);
          unsigned long long n1 = cm & (cm - 1);
          int c1 = n1 ? (int)__builtin_ctzll(n1) : c0;
          unsigned long long n2 = n1 ? (n1 & (n1 - 1)) : 0;
          int c2 = n2 ? (int)__builtin_ctzll(n2) : c0;
          unsigned long long n3 = n2 ? (n2 & (n2 - 1)) : 0;
          int c3 = n3 ? (int)__builtin_ctzll(n3) : c0;
          cm = n3 ? (n3 & (n3 - 1)) : 0;
          float ta0 = Tl[c0 * 68 + lane], tb0 = Tl[c0 * 68 + j2col];
          float ta1 = Tl[c1 * 68 + lane], tb1 = Tl[c1 * 68 + j2col];
          float ta2 = Tl[c2 * 68 + lane], tb2 = Tl[c2 * 68 + j2col];
          float ta3 = Tl[c3 * 68 + lane], tb3 = Tl[c3 * 68 + j2col];
          float v0 = rdlane(s0, c0), v1 = rdlane(s0, c1);
          float v2 = rdlane(s0, c2), v3 = rdlane(s0, c3);
          float x;
          x = v0 + ta0; if (x > m0) { m0 = x; a0i = c0; }
          x = v1 + ta1; if (x > m0) { m0 = x; a0i = c1; }
          x = v2 + ta2; if (x > m0) { m0 = x; a0i = c2; }
          x = v3 + ta3; if (x > m0) { m0 = x; a0i = c3; }
          x = v0 + tb0; if (x > m1) { m1 = x; a1i = c0; }
          x = v1 + tb1; if (x > m1) { m1 = x; a1i = c1; }
          x = v2 + tb2; if (x > m1) { m1 = x; a1i = c2; }
          x = v3 + tb3; if (x > m1) { m1 = x; a1i = c3; }
        }
        while (em) {
          int eb = (int)__builtin_ctz(em);
          em &= em - 1;
          int c = 64 + eb;
          float scc = rdlane(s1, eb);
          float x0 = scc + Tl[c * 68 + lane];
          float x1 = scc + Tl[c * 68 + j2col];
          if (x0 > m0) { m0 = x0; a0i = c; }
          if (x1 > m1) { m1 = x1; a1i = c; }
        }
        h1f[t * 68 + lane] = (unsigned char)a0i;
        if (lane < 3) h1f[t * 68 + 64 + lane] = (unsigned char)a1i;
        // path composition (exact integer gather of backpointers)
        int gA = __shfl(cmp, a0i & 63);
        int gB = __shfl(cmp2, (a0i >= 64) ? (a0i - 64) : 0);
        int nc = (a0i < 64) ? gA : gB;
        int gA2 = __shfl(cmp, a1i & 63);
        int gB2 = __shfl(cmp2, (a1i >= 64) ? (a1i - 64) : 0);
        int nc2 = (a1i < 64) ? gA2 : gB2;
        cmp = nc;
        cmp2 = nc2;
        if ((t & 63) == 0) {  // t = 64,128,192
          int slot = t >> 6;
          ckF[slot * 68 + lane] = (unsigned char)cmp;
          if (lane < 3) ckF[slot * 68 + 64 + lane] = (unsigned char)cmp2;
          cmp = lane;
          cmp2 = 64 + lane;
        }
        s0 = m0 + e0;
        if (lane < 3) s1 = m1 + e1;
      }
      fj[lane] = s0;
      if (lane < 3) fj[64 + lane] = s1;
      __syncthreads();  // #1 scans done
      __syncthreads();  // #2 junction done
      int jstar = ji[0];
      for (int p = len + lane; p < NL; p += 64) out[p] = 0.f;
      // chain starts via checkpoints
      int gA = __shfl(cmp, jstar & 63);
      int gB = __shfl(cmp2, (jstar >= 64) ? (jstar - 64) : 0);
      int s192 = (jstar < 64) ? gA : gB;
      int s128 = ckF[3 * 68 + s192];
      int s64 = ckF[2 * 68 + s128];
      if (lane < 4) {
        int cur;
        if (lane == 3) cur = jstar;
        else if (lane == 2) cur = h1f[192 * 68 + s192];
        else if (lane == 1) cur = h1f[128 * 68 + s128];
        else cur = h1f[64 * 68 + s64];
        int base = lane * 64;
        for (int s = 0; s < 64; ++s) {
          int p = base + 63 - s;
          out[p] = (float)cur;
          if (p > 0) cur = h1f[p * 68 + cur];
        }
      }
    } else {
      // ---- backward half with fwd-pointers + checkpoints ----
      const int i2 = 64 + (lane & 3);
      int cmpB = lane, cmpB2 = 64 + lane;
      float b0 = 0.f, b1 = -INFINITY;
      if (len > 256) {
        b0 = sc[(size_t)(len - 1) * NT + lane] + endv[lane];
        b1 = (lane < 3) ? (sc[(size_t)(len - 1) * NT + 64 + lane] + endv[64 + lane])
                        : -INFINITY;
        float eA0 = sc[(size_t)(len - 2) * NT + lane];
        float eA1 = (lane < 3) ? sc[(size_t)(len - 2) * NT + 64 + lane] : 0.f;
        float eB0 = sc[(size_t)(len - 3) * NT + lane];
        float eB1 = (lane < 3) ? sc[(size_t)(len - 3) * NT + 64 + lane] : 0.f;
        for (int t = len - 2; t >= 256; --t) {
          float e0 = eA0, e1 = eA1;
          eA0 = eB0;
          eA1 = eB1;
          if (t > 257) {
            eB0 = sc[(t - 2) * NT + lane];
            eB1 = (lane < 3) ? sc[(t - 2) * NT + 64 + lane] : 0.f;
          }
          float Bmax = wave_max_dpp(fmaxf(b0, b1));
          float thr = Bmax + trspan;
          unsigned long long cm = __ballot(b0 >= thr);
          unsigned em = (unsigned)__ballot((lane < 3) && (b1 >= thr)) & 7u;
          float m0 = -INFINITY, m1 = -INFINITY;
          int a0i = 0, a1i = 0;
          while (cm) {
            int c0 = (int)__builtin_ctzll(cm);
            unsigned long long n1 = cm & (cm - 1);
            int c1 = n1 ? (int)__builtin_ctzll(n1) : c0;
            unsigned long long n2 = n1 ? (n1 & (n1 - 1)) : 0;
            int c2 = n2 ? (int)__builtin_ctzll(n2) : c0;
            unsigned long long n3 = n2 ? (n2 & (n2 - 1)) : 0;
            int c3 = n3 ? (int)__builtin_ctzll(n3) : c0;
            cm = n3 ? (n3 & (n3 - 1)) : 0;
            float ta0 = TlT[c0 * 68 + lane], tb0 = TlT[c0 * 68 + i2];
            float ta1 = TlT[c1 * 68 + lane], tb1 = TlT[c1 * 68 + i2];
            float ta2 = TlT[c2 * 68 + lane], tb2 = TlT[c2 * 68 + i2];
            float ta3 = TlT[c3 * 68 + lane], tb3 = TlT[c3 * 68 + i2];
            float v0 = rdlane(b0, c0), v1 = rdlane(b0, c1);
            float v2 = rdlane(b0, c2), v3 = rdlane(b0, c3);
            float x;
            x = v0 + ta0; if (x > m0) { m0 = x; a0i = c0; }
            x = v1 + ta1; if (x > m0) { m0 = x; a0i = c1; }
            x = v2 + ta2; if (x > m0) { m0 = x; a0i = c2; }
            x = v3 + ta3; if (x > m0) { m0 = x; a0i = c3; }
            x = v0 + tb0; if (x > m1) { m1 = x; a1i = c0; }
            x = v1 + tb1; if (x > m1) { m1 = x; a1i = c1; }
            x = v2 + tb2; if (x > m1) { m1 = x; a1i = c2; }
            x = v3 + tb3; if (x > m1) { m1 = x; a1i = c3; }
          }
          while (em) {
            int eb = (int)__builtin_ctz(em);
            em &= em - 1;
            int c = 64 + eb;
            float scc = rdlane(b1, eb);
            float x0 = scc + TlT[c * 68 + lane];
            float x1 = scc + TlT[c * 68 + i2];
            if (x0 > m0) { m0 = x0; a0i = c; }
            if (x1 > m1) { m1 = x1; a1i = c; }
          }
          gp[(t + 1 - 256) * 68 + lane] = (unsigned char)a0i;
          if (lane < 3) gp[(t + 1 - 256) * 68 + 64 + lane] = (unsigned char)a1i;
          // composition (state@t -> anchor above)
          int gA = __shfl(cmpB, a0i & 63);
          int gB = __shfl(cmpB2, (a0i >= 64) ? (a0i - 64) : 0);
          int nc = (a0i < 64) ? gA : gB;
          int gA2 = __shfl(cmpB, a1i & 63);
          int gB2 = __shfl(cmpB2, (a1i >= 64) ? (a1i - 64) : 0);
          int nc2 = (a1i < 64) ? gA2 : gB2;
          cmpB = nc;
          cmpB2 = nc2;
          if (t == 448 || t == 384 || t == 320) {
            int slot = (t - 320) >> 6;  // 2,1,0
            ckB[slot * 68 + lane] = (unsigned char)cmpB;
            if (lane < 3) ckB[slot * 68 + 64 + lane] = (unsigned char)cmpB2;
            cmpB = lane;
            cmpB2 = 64 + lane;
          }
          b0 = e0 + m0;
          if (lane < 3) b1 = e1 + m1;
        }
        bj[lane] = b0;
        if (lane < 3) bj[64 + lane] = b1;
      }
      __syncthreads();  // #1 scans done
      // junction
      float ci, ci2;
      int jpi = 0, jpi2 = 0;
      if (len > 256) {
        ci = -INFINITY;
        ci2 = -INFINITY;
        for (int j = 0; j < NT; ++j) {
          float bv = bj[j];
          float x = TlT[j * 68 + lane] + bv;
          if (x > ci) { ci = x; jpi = j; }
          if (lane < 3) {
            float x2 = TlT[j * 68 + 64 + lane] + bv;
            if (x2 > ci2) { ci2 = x2; jpi2 = j; }
          }
        }
      } else {
        ci = endv[lane];
        ci2 = (lane < 3) ? endv[64 + lane] : -INFINITY;
      }
      float v0 = fj[lane] + ci;
      float v1 = (lane < 3) ? (fj[64 + lane] + ci2) : -INFINITY;
      float bv_;
      int bi_;
      if (v1 > v0) { bv_ = v1; bi_ = 64 + lane; } else { bv_ = v0; bi_ = lane; }
#pragma unroll
      for (int o = 32; o > 0; o >>= 1) {
        float ov = __shfl_xor(bv_, o);
        int oi = __shfl_xor(bi_, o);
        if (ov > bv_ || (ov == bv_ && oi < bi_)) { bv_ = ov; bi_ = oi; }
      }
      jp[lane] = jpi;
      if (lane < 3) jp[64 + lane] = jpi2;
      LGKM_BARRIER();
      int s256 = (len > 256) ? jp[bi_] : 0;
      if (lane == 0) {
        ji[0] = bi_;
        ji[1] = s256;
      }
      __syncthreads();  // #2 junction published
      if (len > 256) {
        // chain starts
        int s320 = 0, s384 = 0, s448 = 0;
        if (len > 320) {
          int gA = __shfl(cmpB, s256 & 63);
          int gB = __shfl(cmpB2, (s256 >= 64) ? (s256 - 64) : 0);
          s320 = (s256 < 64) ? gA : gB;
        }
        if (len > 384) s384 = ckB[0 * 68 + s320];
        if (len > 448) s448 = ckB[1 * 68 + s384];
        if (lane < 4) {
          int t_c = 256 + lane * 64;
          if (t_c < len) {
            int cur = (lane == 0) ? s256 : (lane == 1) ? s320 : (lane == 2) ? s384 : s448;
            int stop = min(t_c + 64, len);
            for (int p = t_c; p < stop; ++p) {
              out[p] = (float)cur;
              cur = gp[(p + 1 - 256) * 68 + cur];  // last read unused
            }
          }
        }
      }
    }
  }
}

// ---------------- K3: den = lse(alpha+beta); loss = -sum(num-den)/B --------
__global__ __launch_bounds__(256) void k_final(const float* __restrict__ wsA,
                                               const float* __restrict__ wsB,
                                               const float* __restrict__ wsNum,
                                               float* __restrict__ out) {
  const int tid = threadIdx.x;
  const int w = tid >> 6, lane = tid & 63;
  float acc = 0.f;
  for (int s = w; s < NB; s += 4) {
    float v = wsA[s * 68 + lane] + wsB[s * 68 + lane];
    float v2 = (lane < 3) ? (wsA[s * 68 + 64 + lane] + wsB[s * 68 + 64 + lane])
                          : -INFINITY;
    float M = wave_max_dpp(fmaxf(v, v2));
    float e = __expf(v - M) + ((lane < 3) ? __expf(v2 - M) : 0.f);
    float den = M + __logf(wave_sum_dpp(e));
    acc += wsNum[s] - den;
  }
  __shared__ float part[4];
  if (lane == 0) part[w] = acc;
  __syncthreads();
  if (tid == 0) out[0] = -(part[0] + part[1] + part[2] + part[3]) / (float)NB;
}

extern "C" void kernel_launch(void* const* d_in, const int* in_sizes, int n_in,
                              void* d_out, int out_size, void* d_ws, size_t ws_size,
                              hipStream_t stream) {
  const float* hidden = (const float*)d_in[0];
  const float* W = (const float*)d_in[1];
  const float* bias = (const float*)d_in[2];
  const float* startv = (const float*)d_in[3];
  const float* endv = (const float*)d_in[4];
  const float* trans = (const float*)d_in[5];
  const int* labels = (const int*)d_in[6];
  const int* maskp = (const int*)d_in[7];
  float* out = (float*)d_out;

  float* scores = (float*)d_ws;  // 32*512*67 f32 = 4.39 MB
  float* wsA = scores + (size_t)NB * NL * NT;
  float* wsB = wsA + NB * 68;
  float* wsNum = wsB + NB * 68;

  hipLaunchKernelGGL(k_scores, dim3((NB * NL) / 64), dim3(256), 0, stream,
                     hidden, W, bias, scores);
  hipLaunchKernelGGL(k_scan, dim3(2 * NB), dim3(128), LDSV, stream,
                     scores, trans, startv, endv, labels, maskp,
                     wsA, wsB, wsNum, out + 1);
  hipLaunchKernelGGL(k_final, dim3(1), dim3(256), 0, stream,
                     wsA, wsB, wsNum, out);
}